// Round 4
// baseline (57244.110 us; speedup 1.0000x reference)
//
#include <hip/hip_runtime.h>

typedef __attribute__((ext_vector_type(8))) short bf8v;   // 8 x bf16
typedef __attribute__((ext_vector_type(4))) float fx4;    // MFMA accumulator
typedef unsigned short u16;
typedef unsigned int u32;

__device__ __forceinline__ float b2f(u16 h) {
    u32 u = ((u32)h) << 16; float f; __builtin_memcpy(&f, &u, 4); return f;
}
__device__ __forceinline__ u16 f2b(float f) {
    u32 u; __builtin_memcpy(&u, &f, 4);
    return (u16)((u + 0x7fffu + ((u >> 16) & 1u)) >> 16);
}

// scalar load, dtype-templated
template<bool F32>
__device__ __forceinline__ float ld1(const void* p, long off) {
    if constexpr (F32) return ((const float*)p)[off];
    else return b2f(((const u16*)p)[off]);
}
// 8-element bf16 fragment load, dtype-templated
template<bool F32>
__device__ __forceinline__ bf8v ld8(const void* p, long off) {
    if constexpr (!F32) {
        return *(const bf8v*)((const u16*)p + off);
    } else {
        const float* f = (const float*)p + off;
        bf8v r;
#pragma unroll
        for (int j = 0; j < 8; ++j) r[j] = (short)f2b(f[j]);
        return r;
    }
}

__device__ __forceinline__ float gru_out(float sr, float sz, float sn, float xn,
                                         float bxr, float bxz, float bxn,
                                         float bhr, float bhz, float bhn, float hp) {
    float r = 1.f / (1.f + __expf(-(sr + bxr + bhr)));
    float z = 1.f / (1.f + __expf(-(sz + bxz + bhz)));
    float pn = xn + bxn + r * (sn + bhn);
    pn = fminf(fmaxf(pn, -15.f), 15.f);
    float e = __expf(2.f * pn);
    float n = (e - 1.f) / (e + 1.f);
    return n + z * (hp - n);
}

// ---------------------------------------------------------------- zero zbuf (32 blocks x 4096 B = 131072 B)
__global__ __launch_bounds__(256) void zero16(uint4* __restrict__ p) {
    p[(long)blockIdx.x * 256 + threadIdx.x] = make_uint4(0u, 0u, 0u, 0u);
}

// ---------------------------------------------------------------- flags[0]: 1 = inputs fp32, 0 = bf16
__global__ __launch_bounds__(256) void detect_dtype(const u32* __restrict__ x,
                                                    u32* __restrict__ flags) {
    __shared__ int red[256];
    int t = threadIdx.x;
    int cnt = 0;
    for (int i = t; i < 4096; i += 256) {
        u32 ex = (x[i] >> 7) & 0xff;      // exponent of low half viewed as bf16
        cnt += (ex >= 100 && ex <= 135) ? 1 : 0;
    }
    red[t] = cnt; __syncthreads();
    for (int s = 128; s > 0; s >>= 1) { if (t < s) red[t] += red[t + s]; __syncthreads(); }
    if (t == 0) flags[0] = (red[0] < 2048) ? 1u : 0u;
}

// ---------------------------------------------------------------- flags[1]: layout-A ok, flags[2]: layout-B ok
// Layout A (assumed): A[m=l&15][k=(l>>4)*8+j], B[k=(l>>4)*8+j][n=l&15],
//                     C/D: col=l&15, row=(l>>4)*4+reg.   Layout B: C/D swapped.
__global__ __launch_bounds__(64) void selftest_mfma(u32* __restrict__ flags) {
    __shared__ float Af[16 * 32], Bf[32 * 16];
    __shared__ int okA, okB;
    int t = threadIdx.x;
    if (t == 0) { okA = 1; okB = 1; }
    for (int i = t; i < 512; i += 64) {
        int m = i >> 5, k = i & 31;
        Af[i] = (float)(((m * 7 + k * 13) % 17) - 8);
        int kk = i >> 4, n = i & 15;
        Bf[i] = (float)(((kk * 5 + n * 3) % 19) - 9);
    }
    __syncthreads();
    int l15 = t & 15, lk = t >> 4;
    bf8v a, b;
#pragma unroll
    for (int j = 0; j < 8; ++j) {
        a[j] = (short)f2b(Af[l15 * 32 + lk * 8 + j]);
        b[j] = (short)f2b(Bf[(lk * 8 + j) * 16 + l15]);
    }
    fx4 acc = {0.f, 0.f, 0.f, 0.f};
    acc = __builtin_amdgcn_mfma_f32_16x16x32_bf16(a, b, acc, 0, 0, 0);
    int gA = 1, gB = 1;
    for (int reg = 0; reg < 4; ++reg) {
        int rA = lk * 4 + reg, cA = l15;
        int rB = l15, cB = lk * 4 + reg;
        float refA = 0.f, refB = 0.f;
        for (int k = 0; k < 32; ++k) {
            refA += Af[rA * 32 + k] * Bf[k * 16 + cA];
            refB += Af[rB * 32 + k] * Bf[k * 16 + cB];
        }
        if (fabsf(acc[reg] - refA) > 0.5f) gA = 0;
        if (fabsf(acc[reg] - refB) > 0.5f) gB = 0;
    }
    if (!gA) atomicAnd(&okA, 0);
    if (!gB) atomicAnd(&okB, 0);
    __syncthreads();
    if (t == 0) { flags[1] = (u32)okA; flags[2] = (okA ? 0u : (u32)okB); }
}

// ================================================================ GRU step bodies
// 64 blocks x 64 threads. Block = 16 hidden units x 64 batch x 3 gates.
// h_in: [64][1024] bf16. x row b at xp+xoff+b*xstride (dtype XF32). Weights/biases dtype WF32.
template<bool WF32, bool XF32, bool MAPA>
__device__ void step_mfma(const u16* __restrict__ h_in,
                          const void* __restrict__ xp, long xoff, long xstride,
                          const void* __restrict__ Wx, const void* __restrict__ Wh,
                          const void* __restrict__ bx, const void* __restrict__ bh,
                          u16* __restrict__ h_out) {
    int u0 = blockIdx.x * 16;
    int l = threadIdx.x, l15 = l & 15, lk = l >> 4;
    fx4 aR[4] = {}, aZ[4] = {}, aN[4] = {}, aXN[4] = {};

    for (int kk = 0; kk < 1024; kk += 32) {             // h @ Wh^T
        bf8v a[4];
#pragma unroll
        for (int m = 0; m < 4; ++m)
            a[m] = *(const bf8v*)&h_in[(long)(m * 16 + l15) * 1024 + kk + lk * 8];
        bf8v bR = ld8<WF32>(Wh, (long)(u0 + l15) * 1024 + kk + lk * 8);
        bf8v bZ = ld8<WF32>(Wh, (long)(1024 + u0 + l15) * 1024 + kk + lk * 8);
        bf8v bN = ld8<WF32>(Wh, (long)(2048 + u0 + l15) * 1024 + kk + lk * 8);
#pragma unroll
        for (int m = 0; m < 4; ++m) {
            aR[m] = __builtin_amdgcn_mfma_f32_16x16x32_bf16(a[m], bR, aR[m], 0, 0, 0);
            aZ[m] = __builtin_amdgcn_mfma_f32_16x16x32_bf16(a[m], bZ, aZ[m], 0, 0, 0);
            aN[m] = __builtin_amdgcn_mfma_f32_16x16x32_bf16(a[m], bN, aN[m], 0, 0, 0);
        }
    }
    for (int kk = 0; kk < 1024; kk += 32) {             // x @ Wx^T (n-gate kept separate)
        bf8v a[4];
#pragma unroll
        for (int m = 0; m < 4; ++m)
            a[m] = ld8<XF32>(xp, xoff + (long)(m * 16 + l15) * xstride + kk + lk * 8);
        bf8v bR = ld8<WF32>(Wx, (long)(u0 + l15) * 1024 + kk + lk * 8);
        bf8v bZ = ld8<WF32>(Wx, (long)(1024 + u0 + l15) * 1024 + kk + lk * 8);
        bf8v bN = ld8<WF32>(Wx, (long)(2048 + u0 + l15) * 1024 + kk + lk * 8);
#pragma unroll
        for (int m = 0; m < 4; ++m) {
            aR[m]  = __builtin_amdgcn_mfma_f32_16x16x32_bf16(a[m], bR, aR[m], 0, 0, 0);
            aZ[m]  = __builtin_amdgcn_mfma_f32_16x16x32_bf16(a[m], bZ, aZ[m], 0, 0, 0);
            aXN[m] = __builtin_amdgcn_mfma_f32_16x16x32_bf16(a[m], bN, aXN[m], 0, 0, 0);
        }
    }
#pragma unroll
    for (int m = 0; m < 4; ++m)
#pragma unroll
        for (int reg = 0; reg < 4; ++reg) {
            int bi, u;
            if (MAPA) { bi = m * 16 + lk * 4 + reg; u = u0 + l15; }
            else      { bi = m * 16 + l15;          u = u0 + lk * 4 + reg; }
            float bxr = ld1<WF32>(bx, u),        bhr = ld1<WF32>(bh, u);
            float bxz = ld1<WF32>(bx, 1024 + u), bhz = ld1<WF32>(bh, 1024 + u);
            float bxn = ld1<WF32>(bx, 2048 + u), bhn = ld1<WF32>(bh, 2048 + u);
            float hp = b2f(h_in[(long)bi * 1024 + u]);
            float hv = gru_out(aR[m][reg], aZ[m][reg], aN[m][reg], aXN[m][reg],
                               bxr, bxz, bxn, bhr, bhz, bhn, hp);
            h_out[(long)bi * 1024 + u] = f2b(hv);
        }
}

// layout-free VALU fallback (slow, correctness insurance)
template<bool WF32, bool XF32>
__device__ void step_valu(const u16* __restrict__ h_in,
                          const void* __restrict__ xp, long xoff, long xstride,
                          const void* __restrict__ Wx, const void* __restrict__ Wh,
                          const void* __restrict__ bx, const void* __restrict__ bh,
                          u16* __restrict__ h_out) {
    int u0 = blockIdx.x * 16;
    int t = threadIdx.x;
    for (int p = t; p < 1024; p += 64) {
        int b = p & 63, uu = u0 + (p >> 6);
        float sr = 0, sz = 0, sn = 0, xr = 0, xz = 0, xn = 0;
        for (int k = 0; k < 1024; ++k) {
            float hv = b2f(h_in[(long)b * 1024 + k]);
            float xv = ld1<XF32>(xp, xoff + (long)b * xstride + k);
            sr += hv * ld1<WF32>(Wh, (long)uu * 1024 + k);
            sz += hv * ld1<WF32>(Wh, (long)(1024 + uu) * 1024 + k);
            sn += hv * ld1<WF32>(Wh, (long)(2048 + uu) * 1024 + k);
            xr += xv * ld1<WF32>(Wx, (long)uu * 1024 + k);
            xz += xv * ld1<WF32>(Wx, (long)(1024 + uu) * 1024 + k);
            xn += xv * ld1<WF32>(Wx, (long)(2048 + uu) * 1024 + k);
        }
        float hv = gru_out(sr + xr, sz + xz, sn, xn,
                           ld1<WF32>(bx, uu), ld1<WF32>(bx, 1024 + uu), ld1<WF32>(bx, 2048 + uu),
                           ld1<WF32>(bh, uu), ld1<WF32>(bh, 1024 + uu), ld1<WF32>(bh, 2048 + uu),
                           b2f(h_in[(long)b * 1024 + uu]));
        h_out[(long)b * 1024 + uu] = f2b(hv);
    }
}

__global__ __launch_bounds__(64) void gru_step2(const u16* __restrict__ h_in,
                                                const void* __restrict__ xp, long xoff, long xstride,
                                                const void* __restrict__ Wx, const void* __restrict__ Wh,
                                                const void* __restrict__ bx, const void* __restrict__ bh,
                                                const u32* __restrict__ flags, int x_is_harness_dtype,
                                                u16* __restrict__ h_out) {
    bool wf32 = flags[0] != 0;
    bool xf32 = wf32 && (x_is_harness_dtype != 0);
    if (flags[1]) {
        if (!wf32)      step_mfma<false, false, true>(h_in, xp, xoff, xstride, Wx, Wh, bx, bh, h_out);
        else if (xf32)  step_mfma<true, true, true>(h_in, xp, xoff, xstride, Wx, Wh, bx, bh, h_out);
        else            step_mfma<true, false, true>(h_in, xp, xoff, xstride, Wx, Wh, bx, bh, h_out);
    } else if (flags[2]) {
        if (!wf32)      step_mfma<false, false, false>(h_in, xp, xoff, xstride, Wx, Wh, bx, bh, h_out);
        else if (xf32)  step_mfma<true, true, false>(h_in, xp, xoff, xstride, Wx, Wh, bx, bh, h_out);
        else            step_mfma<true, false, false>(h_in, xp, xoff, xstride, Wx, Wh, bx, bh, h_out);
    } else {
        if (!wf32)      step_valu<false, false>(h_in, xp, xoff, xstride, Wx, Wh, bx, bh, h_out);
        else if (xf32)  step_valu<true, true>(h_in, xp, xoff, xstride, Wx, Wh, bx, bh, h_out);
        else            step_valu<true, false>(h_in, xp, xoff, xstride, Wx, Wh, bx, bh, h_out);
    }
}

// ---------------------------------------------------------------- final FC: fp32 OUTPUT (the round-3 finding)
__global__ __launch_bounds__(256) void fc_out(const u16* __restrict__ h,
                                              const void* __restrict__ fcW,
                                              const void* __restrict__ fcb,
                                              const u32* __restrict__ flags,
                                              float* __restrict__ out) {
    bool f32 = flags[0] != 0;
    __shared__ float red[256];
    int t = threadIdx.x, b = t >> 2, q = t & 3;
    float s = 0.f;
    for (int u = q * 256; u < q * 256 + 256; ++u) {
        float w = f32 ? ((const float*)fcW)[u] : b2f(((const u16*)fcW)[u]);
        s += b2f(h[(long)b * 1024 + u]) * w;
    }
    red[t] = s; __syncthreads();
    if (q == 0) {
        float fb = f32 ? ((const float*)fcb)[0] : b2f(((const u16*)fcb)[0]);
        out[b] = red[t] + red[t + 1] + red[t + 2] + red[t + 3] + fb;
    }
}

// ================================================================ host
extern "C" void kernel_launch(void* const* d_in, const int* in_sizes, int n_in,
                              void* d_out, int out_size, void* d_ws, size_t ws_size,
                              hipStream_t stream) {
    (void)in_sizes; (void)n_in; (void)out_size; (void)ws_size;
    char* ws = (char*)d_ws;
    u16* zbuf = (u16*)ws;                 // 131072 B of zeros (initial h for both layers)
    u16* h0a  = (u16*)(ws + 131072);
    u16* h0b  = (u16*)(ws + 262144);
    u16* h1a  = (u16*)(ws + 393216);
    u16* h1b  = (u16*)(ws + 524288);
    u32* flags = (u32*)(ws + 655360);

    zero16<<<32, 256, 0, stream>>>((uint4*)d_ws);               // zbuf only
    detect_dtype<<<1, 256, 0, stream>>>((const u32*)d_in[0], flags);
    selftest_mfma<<<1, 64, 0, stream>>>(flags);

    const void* x   = d_in[0];
    const void* Wx0 = d_in[1]; const void* bx0 = d_in[2];
    const void* Wh0 = d_in[3]; const void* bh0 = d_in[4];
    const void* Wx1 = d_in[5]; const void* bx1 = d_in[6];
    const void* Wh1 = d_in[7]; const void* bh1 = d_in[8];
    const void* fcW = d_in[9]; const void* fcb = d_in[10];

    u16 *h0c = h0a, *h0n = h0b, *h1c = h1a, *h1n = h1b;
    for (int t = 0; t < 512; ++t) {
        const u16* hin0 = t ? h0c : zbuf;
        gru_step2<<<64, 64, 0, stream>>>(hin0, x, (long)t * 1024, 512L * 1024,
                                         Wx0, Wh0, bx0, bh0, flags, 1, h0n);
        const u16* hin1 = t ? h1c : zbuf;
        gru_step2<<<64, 64, 0, stream>>>(hin1, h0n, 0, 1024,
                                         Wx1, Wh1, bx1, bh1, flags, 0, h1n);
        u16* tmp = h0c; h0c = h0n; h0n = tmp;
        tmp = h1c; h1c = h1n; h1n = tmp;
    }
    fc_out<<<1, 256, 0, stream>>>(h1c, fcW, fcb, flags, (float*)d_out);
}